// Round 4
// baseline (34.837 us; speedup 1.0000x reference)
//
#include <hip/hip_runtime.h>
#include <math.h>

// Problem constants
#define Dq 512
#define Vq 50257
#define Kq 100
#define KP 112              // K padded to 7*16
#define NORM_TERM 10.8249051f   // log(50257)
#define LOGK 4.6051702f         // log(100)
#define NBLK 1024           // 16384 positions / 16 per block

typedef __attribute__((ext_vector_type(8))) short short8;
typedef __attribute__((ext_vector_type(4))) float floatx4;
typedef __attribute__((ext_vector_type(4))) unsigned short ushort4v;

__device__ __forceinline__ unsigned short f2bf(float f) {
    union { float f; unsigned u; } v; v.f = f;
    unsigned r = v.u + 0x7FFFu + ((v.u >> 16) & 1u);   // RNE
    return (unsigned short)(r >> 16);
}

__device__ __forceinline__ float log_sigmoid(float x) {
    // log(sigmoid(x)) = min(x,0) - log(1 + exp(-|x|))
    return fminf(x, 0.f) - __logf(1.f + __expf(-fabsf(x)));
}

// Gather + convert noise embedding rows to bf16 [112][512], zero-padded.
// Also precompute per-noise adjustment: bias - NORM - logprob_noise - logK.
__global__ void prep_noise(const float* __restrict__ emb_w,
                           const float* __restrict__ emb_b,
                           const float* __restrict__ lpn,
                           const int* __restrict__ ns,
                           unsigned short* __restrict__ nB,
                           float* __restrict__ nAdj) {
    int k = blockIdx.x;     // 0..111
    int t = threadIdx.x;    // 0..63
    if (k < Kq) {
        int row = ns[k];
        const floatx4* src = (const floatx4*)(emb_w + (size_t)row * Dq);
        ushort4v* dst = (ushort4v*)(nB + (size_t)k * Dq);
#pragma unroll
        for (int i = 0; i < 2; ++i) {
            floatx4 v = src[t + i * 64];
            ushort4v o;
            o.x = f2bf(v.x); o.y = f2bf(v.y); o.z = f2bf(v.z); o.w = f2bf(v.w);
            dst[t + i * 64] = o;
        }
        if (t == 0) nAdj[k] = emb_b[row] - NORM_TERM - lpn[row] - LOGK;
    } else {
        ushort4v* dst = (ushort4v*)(nB + (size_t)k * Dq);
        ushort4v z; z.x = 0; z.y = 0; z.z = 0; z.w = 0;
        dst[t] = z; dst[t + 64] = z;
        if (t == 0) nAdj[k] = 0.f;
    }
}

// Block = 4 waves = 16 positions. Stage 16 input rows once in LDS (bf16,
// XOR-swizzled). Target tile D-split across ALL 4 waves (balanced HBM
// gather); partial diagonals exchanged via tiny tdiag LDS. Noise k-tiles
// wave-private full-D (no accumulator exchange): w0:{0,1} w1:{2,3}
// w2:{4,5} w3:{6}+target epilogue.
__global__ __launch_bounds__(256, 8) void nce_main(
    const float* __restrict__ input,     // [16384][512]
    const float* __restrict__ emb_w,     // [V][512]
    const float* __restrict__ emb_b,     // [V]
    const float* __restrict__ lpn,       // [V]
    const int* __restrict__ target,      // [16384]
    const unsigned short* __restrict__ nB,   // [112][512] bf16
    const float* __restrict__ nAdj,          // [112]
    float* __restrict__ partials)            // [1024]
{
    // A_lds: bf16 [16][512], byte offset = row*1024 + (col*2 ^ ((row&7)<<4))
    __shared__ unsigned short A_lds[16 * 512];
    __shared__ float tdiag[4][16];     // per-wave partial target diagonals
    __shared__ float blocksum[4];

    int tid  = threadIdx.x;
    int lane = tid & 63;
    int w    = tid >> 6;            // wave id
    int pos0 = (int)blockIdx.x * 16;
    int r16  = lane & 15;
    int g4   = lane >> 4;

    int tgt = target[pos0 + r16];   // every wave: target of position r16

    // ---- Stage 16 input rows -> LDS bf16 (each wave: 4 rows) ----
    {
        int row = w * 4 + g4;                 // 0..15
        const float* src = input + (size_t)(pos0 + row) * Dq;
        char* base = (char*)A_lds + row * 1024;
        int sw = (row & 7) << 4;
#pragma unroll
        for (int j = 0; j < 8; ++j) {
            int c = r16 * 4 + j * 64;         // float col
            floatx4 v = *(const floatx4*)(src + c);
            ushort4v o;
            o.x = f2bf(v.x); o.y = f2bf(v.y); o.z = f2bf(v.z); o.w = f2bf(v.w);
            *(ushort4v*)(base + ((c * 2) ^ sw)) = o;
        }
    }
    __syncthreads();

    // A-frag for global d-tile dt: row r16, byte dt*64 + g4*16 (swizzled)
    const char* abase = (const char*)A_lds + r16 * 1024;
    int asw = (r16 & 7) << 4;

    // ---- Target tile, D-slice [w*128, w*128+128): 4 MFMAs ----
    {
        const float* trow = emb_w + (size_t)tgt * Dq + w * 128 + g4 * 8;
        floatx4 accT = {0.f, 0.f, 0.f, 0.f};
#pragma unroll
        for (int j = 0; j < 4; ++j) {
            int dt = w * 4 + j;
            floatx4 t0 = *(const floatx4*)(trow + j * 32);
            floatx4 t1 = *(const floatx4*)(trow + j * 32 + 4);
            short8 a = *(const short8*)(abase + ((dt * 64 + g4 * 16) ^ asw));
            short8 ft;
            ft[0] = (short)f2bf(t0.x); ft[1] = (short)f2bf(t0.y);
            ft[2] = (short)f2bf(t0.z); ft[3] = (short)f2bf(t0.w);
            ft[4] = (short)f2bf(t1.x); ft[5] = (short)f2bf(t1.y);
            ft[6] = (short)f2bf(t1.z); ft[7] = (short)f2bf(t1.w);
            accT = __builtin_amdgcn_mfma_f32_16x16x32_bf16(a, ft, accT, 0, 0, 0);
        }
        // D[row=g4*4+reg][col=r16]; diag (pos r16) lives where g4 == r16>>2
        if ((r16 >> 2) == g4) tdiag[w][r16] = accT[r16 & 3];
    }

    // ---- Noise tiles (wave-private, full D) ----
    float contrib = 0.f;
    if (w < 3) {
        const unsigned short* b0 = nB + (size_t)(w * 2 * 16 + r16) * Dq + g4 * 8;
        const unsigned short* b1 = b0 + 16 * Dq;
        floatx4 acc0 = {0.f, 0.f, 0.f, 0.f};
        floatx4 acc1 = {0.f, 0.f, 0.f, 0.f};
#pragma unroll
        for (int dt = 0; dt < 16; ++dt) {
            short8 a = *(const short8*)(abase + ((dt * 64 + g4 * 16) ^ asw));
            short8 f0 = *(const short8*)(b0 + dt * 32);
            short8 f1 = *(const short8*)(b1 + dt * 32);
            acc0 = __builtin_amdgcn_mfma_f32_16x16x32_bf16(a, f0, acc0, 0, 0, 0);
            acc1 = __builtin_amdgcn_mfma_f32_16x16x32_bf16(a, f1, acc1, 0, 0, 0);
        }
        float adj0 = nAdj[w * 32 + r16];
        float adj1 = nAdj[w * 32 + 16 + r16];
#pragma unroll
        for (int r = 0; r < 4; ++r) {
            contrib += log_sigmoid(-(acc0[r] + adj0));
            contrib += log_sigmoid(-(acc1[r] + adj1));
        }
    } else {
        const unsigned short* b6 = nB + (size_t)(96 + r16) * Dq + g4 * 8;
        floatx4 acc6 = {0.f, 0.f, 0.f, 0.f};
#pragma unroll
        for (int dt = 0; dt < 16; ++dt) {
            short8 a = *(const short8*)(abase + ((dt * 64 + g4 * 16) ^ asw));
            short8 f6 = *(const short8*)(b6 + dt * 32);
            acc6 = __builtin_amdgcn_mfma_f32_16x16x32_bf16(a, f6, acc6, 0, 0, 0);
        }
        if (96 + r16 < Kq) {
            float adj6 = nAdj[96 + r16];
#pragma unroll
            for (int r = 0; r < 4; ++r)
                contrib += log_sigmoid(-(acc6[r] + adj6));
        }
    }
    __syncthreads();

    // ---- Target epilogue: wave 3 lanes 0..15 own one position each ----
    if (w == 3 && g4 == 0) {
        float at = tdiag[0][r16] + tdiag[1][r16] + tdiag[2][r16] + tdiag[3][r16];
        float xt = at + emb_b[tgt] - NORM_TERM - lpn[tgt] - LOGK;
        contrib += log_sigmoid(xt);
    }

#pragma unroll
    for (int off = 32; off >= 1; off >>= 1)
        contrib += __shfl_xor(contrib, off);
    if (lane == 0) blocksum[w] = contrib;
    __syncthreads();
    if (tid == 0)
        partials[blockIdx.x] = blocksum[0] + blocksum[1] + blocksum[2] + blocksum[3];
}

// Deterministic per-batch reduction, parallel: 256 threads, LDS tree.
__global__ void finalize(const float* __restrict__ partials,
                         float* __restrict__ out) {
    __shared__ float s4[64][5];        // padded
    int t = threadIdx.x;               // 0..255
    int b = t & 63, q = t >> 6;
    float s = 0.f;
#pragma unroll
    for (int i = 0; i < 4; ++i) s += partials[b * 16 + q * 4 + i];
    s4[b][q] = s;
    __syncthreads();
    if (t < 64) out[t] = s4[t][0] + s4[t][1] + s4[t][2] + s4[t][3];
}

extern "C" void kernel_launch(void* const* d_in, const int* in_sizes, int n_in,
                              void* d_out, int out_size, void* d_ws, size_t ws_size,
                              hipStream_t stream) {
    const float* input = (const float*)d_in[0];
    const float* emb_w = (const float*)d_in[1];
    const float* emb_b = (const float*)d_in[2];
    const float* lpn   = (const float*)d_in[3];
    const int*   tgt   = (const int*)d_in[4];
    const int*   ns    = (const int*)d_in[5];
    float* out = (float*)d_out;

    // ws layout: [0,114688) noise bf16; [114688,115200) nAdj(+pad);
    // [115200,119296) partials.
    unsigned short* nB  = (unsigned short*)d_ws;
    float* nAdj     = (float*)((char*)d_ws + (size_t)KP * Dq * 2);
    float* partials = (float*)((char*)d_ws + (size_t)KP * Dq * 2 + 512);

    prep_noise<<<KP, 64, 0, stream>>>(emb_w, emb_b, lpn, ns, nB, nAdj);
    nce_main<<<NBLK, 256, 0, stream>>>(input, emb_w, emb_b, lpn, tgt, nB, nAdj,
                                       partials);
    finalize<<<1, 256, 0, stream>>>(partials, out);
}

// Round 5
// 33.782 us; speedup vs baseline: 1.0312x; 1.0312x over previous
//
#include <hip/hip_runtime.h>
#include <math.h>

// Problem constants
#define Dq 512
#define Vq 50257
#define Kq 100
#define KP 112              // K padded to 7*16
#define NORM_TERM 10.8249051f   // log(50257)
#define LOGK 4.6051702f         // log(100)
#define NBLK 1024           // 16384 positions / 16 per block

typedef __attribute__((ext_vector_type(8))) short short8;
typedef __attribute__((ext_vector_type(4))) float floatx4;
typedef __attribute__((ext_vector_type(4))) unsigned short ushort4v;
typedef __attribute__((ext_vector_type(8))) unsigned short ushort8v;

__device__ __forceinline__ unsigned short f2bf(float f) {
    union { float f; unsigned u; } v; v.f = f;
    unsigned r = v.u + 0x7FFFu + ((v.u >> 16) & 1u);   // RNE
    return (unsigned short)(r >> 16);
}

__device__ __forceinline__ float log_sigmoid(float x) {
    return fminf(x, 0.f) - __logf(1.f + __expf(-fabsf(x)));
}

// Gather + convert noise embedding rows to bf16 [112][512], zero-padded.
__global__ void prep_noise(const float* __restrict__ emb_w,
                           const float* __restrict__ emb_b,
                           const float* __restrict__ lpn,
                           const int* __restrict__ ns,
                           unsigned short* __restrict__ nB,
                           float* __restrict__ nAdj) {
    int k = blockIdx.x;     // 0..111
    int t = threadIdx.x;    // 0..127 (one row per block, 16B/lane)
    if (k < Kq) {
        int row = ns[k];
        floatx4 v = ((const floatx4*)(emb_w + (size_t)row * Dq))[t];
        ushort4v o;
        o.x = f2bf(v.x); o.y = f2bf(v.y); o.z = f2bf(v.z); o.w = f2bf(v.w);
        ((ushort4v*)(nB + (size_t)k * Dq))[t] = o;
        if (t == 0) nAdj[k] = emb_b[row] - NORM_TERM - lpn[row] - LOGK;
    } else {
        ushort4v z; z.x = 0; z.y = 0; z.z = 0; z.w = 0;
        ((ushort4v*)(nB + (size_t)k * Dq))[t] = z;
        if (t == 0) nAdj[k] = 0.f;
    }
}

// Block = 4 waves = 16 positions. Target gather loads ISSUED AT ENTRY
// (latency hides under input staging + barrier). Stage 16 input rows to
// LDS bf16 (XOR-swizzled, 32B/lane). After barrier: target MFMA (D-split
// across waves, diag exchanged via tiny LDS), then wave-private full-D
// noise k-tiles (no accumulator exchange).
__global__ __launch_bounds__(256, 4) void nce_main(
    const float* __restrict__ input,     // [16384][512]
    const float* __restrict__ emb_w,     // [V][512]
    const float* __restrict__ emb_b,     // [V]
    const float* __restrict__ lpn,       // [V]
    const int* __restrict__ target,      // [16384]
    const unsigned short* __restrict__ nB,   // [112][512] bf16
    const float* __restrict__ nAdj,          // [112]
    float* __restrict__ partials)            // [1024]
{
    __shared__ unsigned short A_lds[16 * 512];  // byte: row*1024 + (2c ^ ((row&7)<<4))
    __shared__ float tdiag[4][16];
    __shared__ float blocksum[4];

    int tid  = threadIdx.x;
    int lane = tid & 63;
    int w    = tid >> 6;
    int pos0 = (int)blockIdx.x * 16;
    int r16  = lane & 15;
    int g4   = lane >> 4;

    // ---- Issue target gather EARLY (consumed after the barrier) ----
    int tgt = target[pos0 + r16];
    const float* trow = emb_w + (size_t)tgt * Dq + w * 128 + g4 * 8;
    floatx4 t0a = *(const floatx4*)(trow);
    floatx4 t0b = *(const floatx4*)(trow + 4);
    floatx4 t1a = *(const floatx4*)(trow + 32);
    floatx4 t1b = *(const floatx4*)(trow + 36);
    floatx4 t2a = *(const floatx4*)(trow + 64);
    floatx4 t2b = *(const floatx4*)(trow + 68);
    floatx4 t3a = *(const floatx4*)(trow + 96);
    floatx4 t3b = *(const floatx4*)(trow + 100);

    // ---- Stage 16 input rows -> LDS bf16 (each wave 4 rows, 32B/lane) ----
    {
        int row = w * 4 + g4;
        const float* src = input + (size_t)(pos0 + row) * Dq;
        char* base = (char*)A_lds + row * 1024;
        int sw = (row & 7) << 4;
#pragma unroll
        for (int j = 0; j < 4; ++j) {
            int c = r16 * 8 + j * 128;        // float col
            floatx4 x0 = *(const floatx4*)(src + c);
            floatx4 x1 = *(const floatx4*)(src + c + 4);
            ushort8v o;
            o[0] = f2bf(x0.x); o[1] = f2bf(x0.y); o[2] = f2bf(x0.z); o[3] = f2bf(x0.w);
            o[4] = f2bf(x1.x); o[5] = f2bf(x1.y); o[6] = f2bf(x1.z); o[7] = f2bf(x1.w);
            *(ushort8v*)(base + ((c * 2) ^ sw)) = o;
        }
    }
    __syncthreads();

    const char* abase = (const char*)A_lds + r16 * 1024;
    int asw = (r16 & 7) << 4;

    // ---- Target tile, D-slice [w*128, +128): consume early loads ----
    {
        floatx4 accT = {0.f, 0.f, 0.f, 0.f};
        floatx4 ta[4] = {t0a, t1a, t2a, t3a};
        floatx4 tb[4] = {t0b, t1b, t2b, t3b};
#pragma unroll
        for (int j = 0; j < 4; ++j) {
            int dt = w * 4 + j;
            short8 a = *(const short8*)(abase + ((dt * 64 + g4 * 16) ^ asw));
            short8 ft;
            ft[0] = (short)f2bf(ta[j].x); ft[1] = (short)f2bf(ta[j].y);
            ft[2] = (short)f2bf(ta[j].z); ft[3] = (short)f2bf(ta[j].w);
            ft[4] = (short)f2bf(tb[j].x); ft[5] = (short)f2bf(tb[j].y);
            ft[6] = (short)f2bf(tb[j].z); ft[7] = (short)f2bf(tb[j].w);
            accT = __builtin_amdgcn_mfma_f32_16x16x32_bf16(a, ft, accT, 0, 0, 0);
        }
        // D[row=g4*4+reg][col=r16]; diag (pos r16) where g4 == r16>>2
        if ((r16 >> 2) == g4) tdiag[w][r16] = accT[r16 & 3];
    }

    // ---- Noise tiles (wave-private, full D) ----
    float contrib = 0.f;
    if (w < 3) {
        const unsigned short* b0 = nB + (size_t)(w * 2 * 16 + r16) * Dq + g4 * 8;
        const unsigned short* b1 = b0 + 16 * Dq;
        floatx4 acc0 = {0.f, 0.f, 0.f, 0.f};
        floatx4 acc1 = {0.f, 0.f, 0.f, 0.f};
#pragma unroll
        for (int dt = 0; dt < 16; ++dt) {
            short8 a = *(const short8*)(abase + ((dt * 64 + g4 * 16) ^ asw));
            short8 f0 = *(const short8*)(b0 + dt * 32);
            short8 f1 = *(const short8*)(b1 + dt * 32);
            acc0 = __builtin_amdgcn_mfma_f32_16x16x32_bf16(a, f0, acc0, 0, 0, 0);
            acc1 = __builtin_amdgcn_mfma_f32_16x16x32_bf16(a, f1, acc1, 0, 0, 0);
        }
        float adj0 = nAdj[w * 32 + r16];
        float adj1 = nAdj[w * 32 + 16 + r16];
#pragma unroll
        for (int r = 0; r < 4; ++r) {
            contrib += log_sigmoid(-(acc0[r] + adj0));
            contrib += log_sigmoid(-(acc1[r] + adj1));
        }
    } else {
        const unsigned short* b6 = nB + (size_t)(96 + r16) * Dq + g4 * 8;
        floatx4 acc6 = {0.f, 0.f, 0.f, 0.f};
#pragma unroll
        for (int dt = 0; dt < 16; ++dt) {
            short8 a = *(const short8*)(abase + ((dt * 64 + g4 * 16) ^ asw));
            short8 f6 = *(const short8*)(b6 + dt * 32);
            acc6 = __builtin_amdgcn_mfma_f32_16x16x32_bf16(a, f6, acc6, 0, 0, 0);
        }
        if (96 + r16 < Kq) {
            float adj6 = nAdj[96 + r16];
#pragma unroll
            for (int r = 0; r < 4; ++r)
                contrib += log_sigmoid(-(acc6[r] + adj6));
        }
    }
    __syncthreads();

    // ---- Target epilogue: wave 3 lanes 0..15 own one position each ----
    if (w == 3 && g4 == 0) {
        float at = tdiag[0][r16] + tdiag[1][r16] + tdiag[2][r16] + tdiag[3][r16];
        float xt = at + emb_b[tgt] - NORM_TERM - lpn[tgt] - LOGK;
        contrib += log_sigmoid(xt);
    }

#pragma unroll
    for (int off = 32; off >= 1; off >>= 1)
        contrib += __shfl_xor(contrib, off);
    if (lane == 0) blocksum[w] = contrib;
    __syncthreads();
    if (tid == 0)
        partials[blockIdx.x] = blocksum[0] + blocksum[1] + blocksum[2] + blocksum[3];
}

// Deterministic per-batch reduction, parallel: 256 threads, LDS tree.
__global__ void finalize(const float* __restrict__ partials,
                         float* __restrict__ out) {
    __shared__ float s4[64][5];
    int t = threadIdx.x;
    int b = t & 63, q = t >> 6;
    float s = 0.f;
#pragma unroll
    for (int i = 0; i < 4; ++i) s += partials[b * 16 + q * 4 + i];
    s4[b][q] = s;
    __syncthreads();
    if (t < 64) out[t] = s4[t][0] + s4[t][1] + s4[t][2] + s4[t][3];
}

extern "C" void kernel_launch(void* const* d_in, const int* in_sizes, int n_in,
                              void* d_out, int out_size, void* d_ws, size_t ws_size,
                              hipStream_t stream) {
    const float* input = (const float*)d_in[0];
    const float* emb_w = (const float*)d_in[1];
    const float* emb_b = (const float*)d_in[2];
    const float* lpn   = (const float*)d_in[3];
    const int*   tgt   = (const int*)d_in[4];
    const int*   ns    = (const int*)d_in[5];
    float* out = (float*)d_out;

    unsigned short* nB  = (unsigned short*)d_ws;
    float* nAdj     = (float*)((char*)d_ws + (size_t)KP * Dq * 2);
    float* partials = (float*)((char*)d_ws + (size_t)KP * Dq * 2 + 512);

    prep_noise<<<KP, 128, 0, stream>>>(emb_w, emb_b, lpn, ns, nB, nAdj);
    nce_main<<<NBLK, 256, 0, stream>>>(input, emb_w, emb_b, lpn, tgt, nB, nAdj,
                                       partials);
    finalize<<<1, 256, 0, stream>>>(partials, out);
}